// Round 2
// baseline (4486.337 us; speedup 1.0000x reference)
//
#include <hip/hip_runtime.h>
#include <math.h>

#define BATCH 2
#define NHEAD 16
#define SLEN  2048
#define DH    64
#define QB    8          // query rows per block

__device__ __forceinline__ unsigned rotl32(unsigned x, unsigned d) {
    return (x << d) | (x >> (32u - d));
}

// Reproduce jax.random.bernoulli(jax.random.key(42), ...) bits under the
// DEFAULT (JAX >= 0.4.30) jax_threefry_partitionable=True path:
//   counts = iota(uint64, N); counter = (hi32, lo32) = (0, i) for N < 2^32
//   (out0, out1) = threefry2x32(key=(0,42), counter)
//   bits32 = out0 ^ out1
__device__ __forceinline__ unsigned threefry_bits(unsigned i) {
    const unsigned k0 = 0u, k1 = 42u;
    const unsigned ks[3] = { k0, k1, k0 ^ k1 ^ 0x1BD11BDAu };
    unsigned x0 = 0u + ks[0];   // hi counter word = 0
    unsigned x1 = i  + ks[1];   // lo counter word = flat index
    const unsigned rot[2][4] = { {13u,15u,26u,6u}, {17u,29u,16u,24u} };
#pragma unroll
    for (int g = 0; g < 5; ++g) {
#pragma unroll
        for (int r = 0; r < 4; ++r) {
            x0 += x1;
            x1 = rotl32(x1, rot[g & 1][r]);
            x1 ^= x0;
        }
        x0 += ks[(g + 1) % 3];
        x1 += ks[(g + 2) % 3] + (unsigned)(g + 1);
    }
    return x0 ^ x1;
}

__global__ __launch_bounds__(256)
void attn_dropout_kernel(const float* __restrict__ Q,
                         const float* __restrict__ KV,
                         float* __restrict__ O) {
    __shared__ float s_p[QB][SLEN];   // 64 KB: scores then masked probs

    const int blk = blockIdx.x;
    const int bh  = blk / (SLEN / QB);          // 0..31
    const int q0  = (blk % (SLEN / QB)) * QB;   // base query row

    const float* Qbase = Q  + (size_t)bh * SLEN * DH;
    const float* Kbase = KV + (size_t)bh * SLEN * DH;

    const int t = threadIdx.x;
    const int r = t >> 5;      // row within block, 0..7
    const int c = t & 31;      // lane within row, 0..31
    const int q = q0 + r;

    // ---- load this thread's query row into registers (64 floats) ----
    float4 qv[16];
    const float4* q4 = (const float4*)(Qbase + (size_t)q * DH);
#pragma unroll
    for (int i = 0; i < 16; ++i) qv[i] = q4[i];

    // ---- phase 1: scores s[r][k] = (q . k) / 8 ----
    for (int i = 0; i < SLEN / 32; ++i) {
        const int k = c + 32 * i;
        const float4* k4 = (const float4*)(Kbase + (size_t)k * DH);
        float acc = 0.f;
#pragma unroll
        for (int ch = 0; ch < 16; ++ch) {
            float4 kv = k4[ch];
            acc += qv[ch].x * kv.x + qv[ch].y * kv.y
                 + qv[ch].z * kv.z + qv[ch].w * kv.w;
        }
        s_p[r][k] = acc * 0.125f;
    }
    __syncthreads();

    // ---- phase 1.5: row softmax + deterministic dropout ----
    // 32 threads per row; rows occupy aligned 32-lane half-waves, so
    // __shfl_xor with masks 1..16 stays within the row group.
    float m = -INFINITY;
    for (int i = 0; i < SLEN / 32; ++i)
        m = fmaxf(m, s_p[r][c + 32 * i]);
#pragma unroll
    for (int off = 1; off < 32; off <<= 1)
        m = fmaxf(m, __shfl_xor(m, off));

    const unsigned base = (unsigned)bh * (unsigned)(SLEN * SLEN)
                        + (unsigned)q * (unsigned)SLEN;
    float l = 0.f;
    for (int i = 0; i < SLEN / 32; ++i) {
        const int k = c + 32 * i;
        float p = __expf(s_p[r][k] - m);
        l += p;                                   // UNMASKED sum (softmax denom)
        unsigned bits = threefry_bits(base + (unsigned)k);
        float u = __uint_as_float((bits >> 9) | 0x3f800000u) - 1.0f;
        s_p[r][k] = (u < 0.9f) ? p : 0.f;         // keep-mask applied pre-normalization
    }
#pragma unroll
    for (int off = 1; off < 32; off <<= 1)
        l += __shfl_xor(l, off);
    const float scale = 1.0f / (l * 0.9f);        // normalize + /(1-p)
    __syncthreads();

    // ---- phase 2: O[r][d] = scale * sum_k pmask[k] * V[k][d] ----
    // thread owns dims d = c and c+32
    float o0 = 0.f, o1 = 0.f;
    for (int k = 0; k < SLEN; k += 4) {
        float4 p4 = *(const float4*)&s_p[r][k];
        const float* v0 = Kbase + (size_t)k * DH;
        o0 += p4.x * v0[c];          o1 += p4.x * v0[c + 32];
        o0 += p4.y * v0[DH + c];     o1 += p4.y * v0[DH + c + 32];
        o0 += p4.z * v0[2*DH + c];   o1 += p4.z * v0[2*DH + c + 32];
        o0 += p4.w * v0[3*DH + c];   o1 += p4.w * v0[3*DH + c + 32];
    }

    float* orow = O + ((size_t)bh * SLEN + q) * DH;
    orow[c]      = o0 * scale;
    orow[c + 32] = o1 * scale;
}

extern "C" void kernel_launch(void* const* d_in, const int* in_sizes, int n_in,
                              void* d_out, int out_size, void* d_ws, size_t ws_size,
                              hipStream_t stream) {
    const float* x1 = (const float*)d_in[0];   // queries
    const float* x2 = (const float*)d_in[1];   // keys == values
    float* out = (float*)d_out;
    const int nblocks = BATCH * NHEAD * SLEN / QB;   // 8192
    attn_dropout_kernel<<<dim3(nblocks), dim3(256), 0, stream>>>(x1, x2, out);
}

// Round 3
// 422.423 us; speedup vs baseline: 10.6205x; 10.6205x over previous
//
#include <hip/hip_runtime.h>
#include <math.h>

#define BATCH 2
#define NHEAD 16
#define SLEN  2048
#define DH    64
#define WAVES 4            // waves per block
#define QW    16           // q rows per wave
#define QB    (WAVES*QW)   // 64 q rows per block
#define KB    32           // keys per k-step
#define PSTRIDE 36         // dwords per P row in LDS (32 + 4 pad)

typedef __attribute__((ext_vector_type(8))) short bf16x8;
typedef __attribute__((ext_vector_type(4))) float f32x4;

__device__ __forceinline__ unsigned rotl32(unsigned x, unsigned d) {
    return (x << d) | (x >> (32u - d));
}

// jax.random.bernoulli(jax.random.key(42)) bits, jax_threefry_partitionable=True:
// counter = (0, i); bits = out0 ^ out1 of threefry2x32 with key (0, 42).
__device__ __forceinline__ unsigned threefry_bits(unsigned i) {
    const unsigned k0 = 0u, k1 = 42u;
    const unsigned ks2 = k0 ^ k1 ^ 0x1BD11BDAu;
    const unsigned ks[3] = { k0, k1, ks2 };
    unsigned x0 = 0u + ks[0];
    unsigned x1 = i  + ks[1];
    const unsigned rot[2][4] = { {13u,15u,26u,6u}, {17u,29u,16u,24u} };
#pragma unroll
    for (int g = 0; g < 5; ++g) {
#pragma unroll
        for (int r = 0; r < 4; ++r) {
            x0 += x1;
            x1 = rotl32(x1, rot[g & 1][r]);
            x1 ^= x0;
        }
        x0 += ks[(g + 1) % 3];
        x1 += ks[(g + 2) % 3] + (unsigned)(g + 1);
    }
    return x0 ^ x1;
}

__device__ __forceinline__ int keep(unsigned flat) {
    unsigned bits = threefry_bits(flat);
    float u = __uint_as_float((bits >> 9) | 0x3f800000u) - 1.0f;
    return u < 0.9f;
}

// fp32 -> bf16 round-to-nearest-even (no NaN handling needed here)
__device__ __forceinline__ short f2bf(float f) {
    unsigned u = __float_as_uint(f);
    u = (u + 0x7fffu + ((u >> 16) & 1u)) >> 16;
    return (short)u;
}

__global__ __launch_bounds__(256)
void attn_mfma_kernel(const float* __restrict__ Q,
                      const float* __restrict__ KV,
                      float* __restrict__ O) {
    // per-wave P relayout buffer: 16 rows x 36 dwords (32 cols + pad 4)
    __shared__ float s_p[WAVES][QW][PSTRIDE];   // 9216 B

    const int tid  = threadIdx.x;
    const int wave = tid >> 6;
    const int lane = tid & 63;
    const int g    = lane >> 4;    // lane group 0..3
    const int lc   = lane & 15;    // 0..15

    const int blk = blockIdx.x;
    const int bh  = blk >> 5;                  // head index 0..31
    const int q0  = (blk & 31) * QB + wave * QW;

    const float* Qb = Q  + ((size_t)bh * SLEN + q0) * DH;
    const float* Kb = KV + (size_t)bh * SLEN * DH;

    // ---- Q A-fragments (persistent): row=lc, d = 32h + g*8 + j, pre-scaled 1/8 ----
    bf16x8 qa[2];
#pragma unroll
    for (int h = 0; h < 2; ++h) {
        const float* qp = Qb + (size_t)lc * DH + 32 * h + g * 8;
        float4 f0 = *(const float4*)qp;
        float4 f1 = *(const float4*)(qp + 4);
        qa[h][0] = f2bf(f0.x * 0.125f); qa[h][1] = f2bf(f0.y * 0.125f);
        qa[h][2] = f2bf(f0.z * 0.125f); qa[h][3] = f2bf(f0.w * 0.125f);
        qa[h][4] = f2bf(f1.x * 0.125f); qa[h][5] = f2bf(f1.y * 0.125f);
        qa[h][6] = f2bf(f1.z * 0.125f); qa[h][7] = f2bf(f1.w * 0.125f);
    }

    f32x4 oacc[4];
#pragma unroll
    for (int t = 0; t < 4; ++t) oacc[t] = (f32x4){0.f, 0.f, 0.f, 0.f};
    float m[4] = { -INFINITY, -INFINITY, -INFINITY, -INFINITY };
    float l[4] = { 0.f, 0.f, 0.f, 0.f };

    // dropout flat-index base for this lane's row group (rows q0+g*4+i)
    const unsigned rowbase = ((unsigned)bh * SLEN + (unsigned)(q0 + g * 4)) * SLEN;

    for (int k0 = 0; k0 < SLEN; k0 += KB) {
        // ---- K B-fragments: col = key = tt*16+lc, contraction d = 32h + g*8 + j ----
        bf16x8 kb[2][2];
#pragma unroll
        for (int tt = 0; tt < 2; ++tt) {
#pragma unroll
            for (int h = 0; h < 2; ++h) {
                const float* kp = Kb + (size_t)(k0 + tt * 16 + lc) * DH + 32 * h + g * 8;
                float4 f0 = *(const float4*)kp;
                float4 f1 = *(const float4*)(kp + 4);
                kb[tt][h][0] = f2bf(f0.x); kb[tt][h][1] = f2bf(f0.y);
                kb[tt][h][2] = f2bf(f0.z); kb[tt][h][3] = f2bf(f0.w);
                kb[tt][h][4] = f2bf(f1.x); kb[tt][h][5] = f2bf(f1.y);
                kb[tt][h][6] = f2bf(f1.z); kb[tt][h][7] = f2bf(f1.w);
            }
        }

        // ---- S = (Q/8) . K^T : two 16x16 tiles, contraction d=64 via 2 MFMAs ----
        f32x4 s0 = (f32x4){0.f, 0.f, 0.f, 0.f};
        f32x4 s1 = (f32x4){0.f, 0.f, 0.f, 0.f};
        s0 = __builtin_amdgcn_mfma_f32_16x16x32_bf16(qa[0], kb[0][0], s0, 0, 0, 0);
        s0 = __builtin_amdgcn_mfma_f32_16x16x32_bf16(qa[1], kb[0][1], s0, 0, 0, 0);
        s1 = __builtin_amdgcn_mfma_f32_16x16x32_bf16(qa[0], kb[1][0], s1, 0, 0, 0);
        s1 = __builtin_amdgcn_mfma_f32_16x16x32_bf16(qa[1], kb[1][1], s1, 0, 0, 0);

        // ---- online softmax + dropout, per C-reg i (row = q0 + g*4 + i) ----
#pragma unroll
        for (int i = 0; i < 4; ++i) {
            float a = s0[i], b = s1[i];
            float t = fmaxf(a, b);
            t = fmaxf(t, __shfl_xor(t, 1));
            t = fmaxf(t, __shfl_xor(t, 2));
            t = fmaxf(t, __shfl_xor(t, 4));
            t = fmaxf(t, __shfl_xor(t, 8));
            float mnew = fmaxf(m[i], t);
            float corr = __expf(m[i] - mnew);
            float p0 = __expf(a - mnew);
            float p1 = __expf(b - mnew);
            float rs = p0 + p1;                  // UNMASKED row sum
            rs += __shfl_xor(rs, 1);
            rs += __shfl_xor(rs, 2);
            rs += __shfl_xor(rs, 4);
            rs += __shfl_xor(rs, 8);
            l[i] = l[i] * corr + rs;
            m[i] = mnew;
            oacc[0][i] *= corr; oacc[1][i] *= corr;
            oacc[2][i] *= corr; oacc[3][i] *= corr;

            unsigned fi = rowbase + (unsigned)i * SLEN + (unsigned)(k0 + lc);
            if (!keep(fi))       p0 = 0.f;
            if (!keep(fi + 16u)) p1 = 0.f;
            s_p[wave][g * 4 + i][lc]      = p0;
            s_p[wave][g * 4 + i][lc + 16] = p1;
        }

        // ---- P A-fragment readback: row = lc, k = g*8 + j ----
        const float* pp = &s_p[wave][lc][g * 8];
        float4 pf0 = *(const float4*)pp;
        float4 pf1 = *(const float4*)(pp + 4);
        bf16x8 pa;
        pa[0] = f2bf(pf0.x); pa[1] = f2bf(pf0.y);
        pa[2] = f2bf(pf0.z); pa[3] = f2bf(pf0.w);
        pa[4] = f2bf(pf1.x); pa[5] = f2bf(pf1.y);
        pa[6] = f2bf(pf1.z); pa[7] = f2bf(pf1.w);

        // ---- O += P . V : 4 d-tiles, V B-frag: col = d = t*16+lc, k = g*8+j ----
#pragma unroll
        for (int t = 0; t < 4; ++t) {
            bf16x8 vb;
#pragma unroll
            for (int j = 0; j < 8; ++j)
                vb[j] = f2bf(Kb[(size_t)(k0 + g * 8 + j) * DH + t * 16 + lc]);
            oacc[t] = __builtin_amdgcn_mfma_f32_16x16x32_bf16(pa, vb, oacc[t], 0, 0, 0);
        }
    }

    // ---- epilogue: O row q0+g*4+i, col d = t*16+lc ----
#pragma unroll
    for (int i = 0; i < 4; ++i) {
        float sc = 1.0f / (l[i] * 0.9f);
        float* orow = O + ((size_t)bh * SLEN + (size_t)(q0 + g * 4 + i)) * DH;
        orow[lc]      = oacc[0][i] * sc;
        orow[16 + lc] = oacc[1][i] * sc;
        orow[32 + lc] = oacc[2][i] * sc;
        orow[48 + lc] = oacc[3][i] * sc;
    }
}

extern "C" void kernel_launch(void* const* d_in, const int* in_sizes, int n_in,
                              void* d_out, int out_size, void* d_ws, size_t ws_size,
                              hipStream_t stream) {
    const float* x1 = (const float*)d_in[0];   // queries
    const float* x2 = (const float*)d_in[1];   // keys == values
    float* out = (float*)d_out;
    const int nblocks = BATCH * NHEAD * (SLEN / QB);   // 32 * 32 = 1024
    attn_mfma_kernel<<<dim3(nblocks), dim3(256), 0, stream>>>(x1, x2, out);
}